// Round 9
// baseline (438.624 us; speedup 1.0000x reference)
//
#include <hip/hip_runtime.h>
#include <cstdint>

#define N_NODES 20000
#define N_EDGES 320000
#define ALPHA 0.2f
#define GAT_EPS 1e-16f
#define MPAD 20096           // 157 * 128
#define RBLK 157
#define RHI 20               // ceil(157/8)
#define SCAN_BLKS 80
#define BT_ROWS 1152         // 9 col-blocks * 128

typedef __attribute__((ext_vector_type(8))) _Float16 half8;
typedef __attribute__((ext_vector_type(4))) _Float16 half4t;
typedef __attribute__((ext_vector_type(16))) float f32x16;
typedef __attribute__((ext_vector_type(2))) float f32x2;

__device__ __forceinline__ float elu1(float x) { return x > 0.f ? x : __expf(x) - 1.f; }

__device__ __forceinline__ unsigned char f2fp8(float x) {
    return (unsigned char)(__builtin_amdgcn_cvt_pk_fp8_f32(x, 0.f, 0, false) & 0xff);
}

__device__ __forceinline__ void async16(const void* g, void* l) {
    __builtin_amdgcn_global_load_lds(
        (const __attribute__((address_space(1))) unsigned int*)g,
        (__attribute__((address_space(3))) unsigned int*)l, 16, 0, 0);
}

__device__ __forceinline__ float rdlanef(float v, int j) {
    return __int_as_float(__builtin_amdgcn_readlane(__float_as_int(v), j));
}

// packed fp32 fma (VOP3P)
__device__ __forceinline__ f32x2 pkfma(f32x2 a, f32x2 b, f32x2 c) {
    f32x2 d;
    asm("v_pk_fma_f32 %0, %1, %2, %3" : "=v"(d) : "v"(a), "v"(b), "v"(c));
    return d;
}

template <bool HI>
__device__ __forceinline__ f32x2 cvt8(unsigned int u) {
    return __builtin_amdgcn_cvt_pk_f32_fp8((int)u, HI);
}

// ---------------- CSR build ----------------
__global__ void hist_kernel(const int* __restrict__ dst, int* __restrict__ counts, int E) {
    int e = blockIdx.x * blockDim.x + threadIdx.x;
    if (e < E) atomicAdd(&counts[dst[e]], 1);
}

__global__ void scan1_kernel(const int* __restrict__ counts, int* __restrict__ excl,
                             int* __restrict__ partial, int N) {
    __shared__ int sh[256];
    int t = threadIdx.x, b = blockIdx.x;
    int i = b * 256 + t;
    int v = (i < N) ? counts[i] : 0;
    sh[t] = v;
    __syncthreads();
    for (int d = 1; d < 256; d <<= 1) {
        int x = (t >= d) ? sh[t - d] : 0;
        __syncthreads();
        sh[t] += x;
        __syncthreads();
    }
    if (i < N) excl[i] = sh[t] - v;
    if (t == 255) partial[b] = sh[255];
}

__global__ void scan2_kernel(int* __restrict__ partial) {
    __shared__ int sh[128];
    int t = threadIdx.x;
    int v = (t < SCAN_BLKS) ? partial[t] : 0;
    sh[t] = v;
    __syncthreads();
    for (int d = 1; d < 128; d <<= 1) {
        int x = (t >= d) ? sh[t - d] : 0;
        __syncthreads();
        sh[t] += x;
        __syncthreads();
    }
    if (t < SCAN_BLKS) partial[t] = sh[t] - v;
}

__global__ void scan3_kernel(const int* __restrict__ excl, const int* __restrict__ partial,
                             int* __restrict__ rowptr, int* __restrict__ cursor, int N, int E) {
    int t = threadIdx.x, b = blockIdx.x;
    int i = b * 256 + t;
    if (i < N) {
        int v = excl[i] + partial[b];
        rowptr[i] = v;
        cursor[i] = v;
    }
    if (i == 0) rowptr[N] = E;
}

__global__ void scatter_kernel(const int* __restrict__ src, const int* __restrict__ dst,
                               int* __restrict__ cursor, int* __restrict__ esrc, int E) {
    int e = blockIdx.x * blockDim.x + threadIdx.x;
    if (e < E) {
        int p = atomicAdd(&cursor[dst[e]], 1);
        esrc[p] = src[e];
    }
}

// ---------------- packs ----------------
__global__ void pack_x16(const float* __restrict__ x, _Float16* __restrict__ A) {
    int idx = blockIdx.x * 256 + threadIdx.x;   // MPAD*64
    int r = idx >> 6, c = idx & 63;
    float v = (r < N_NODES && c < 50) ? x[r * 50 + c] : 0.f;
    A[idx] = (_Float16)v;
}

__global__ void pack_bt1(const float* __restrict__ W, _Float16* __restrict__ Bt) {
    int idx = blockIdx.x * 256 + threadIdx.x;   // 1024*64
    int c = idx >> 6, k = idx & 63;
    int h = c >> 8, f = c & 255;
    float v = (k < 50) ? W[((size_t)h * 50 + k) * 256 + f] : 0.f;
    Bt[idx] = (_Float16)v;
}

// generic: BT row c -> head h=c/Fpad, col f=c%Fpad; zero for f>=F (alignment pad)
__global__ void pack_bt16(const float* __restrict__ W, _Float16* __restrict__ Bt,
                          int F, int Fpad, int Ctot) {
    int c = blockIdx.y;
    int k = blockIdx.x * blockDim.x + threadIdx.x;
    float v = 0.f;
    if (c < Ctot) {
        int h = c / Fpad, f = c - h * Fpad;
        if (f < F) v = W[(size_t)h * 1024 * F + (size_t)k * F + f];
    }
    Bt[(size_t)c * 1024 + k] = (_Float16)v;
}

// W~ cols appended at BT rows [Nfeat, Nfeat+2H); gridDim.y MUST be 2*H.
__global__ __launch_bounds__(64) void wtilde_kernel(const float* __restrict__ W,
                                                    const float* __restrict__ a,
                                                    _Float16* __restrict__ BT, int Kreal,
                                                    int Kdim, int F, int H, int Nfeat) {
    int k = blockIdx.x, j = blockIdx.y;
    if (j >= 2 * H) return;
    int lane = threadIdx.x;
    int h = j < H ? j : j - H;
    int ao = j < H ? 0 : F;
    float s = 0.f;
    if (k < Kreal) {
        const float* wp = W + ((size_t)h * Kreal + k) * F;
        const float* ap = a + (size_t)h * 2 * F + ao;
        for (int f = lane; f < F; f += 64) s += wp[f] * ap[f];
    }
#pragma unroll
    for (int off = 32; off; off >>= 1) s += __shfl_down(s, off);
    if (lane == 0) BT[(size_t)(Nfeat + j) * Kdim + k] = (_Float16)s;
}

// ---------------- fp16 MFMA GEMM (32x32x16) ----------------
__global__ __launch_bounds__(256) void gemm_f16(const _Float16* __restrict__ A,
                                                const _Float16* __restrict__ BT,
                                                unsigned char* __restrict__ C8,
                                                float* __restrict__ SPRE,
                                                int M, int Nfeat, int ld, int Kdim, int Cblk,
                                                int ldA, int mode) {
    int id = blockIdx.x;
    int xm = id & 7, q = id >> 3;
    int cb = q % Cblk, rh = q / Cblk;
    int rb = rh * 8 + xm;
    if (rb >= RBLK) return;
    __shared__ __align__(16) _Float16 sA[128 * 64];
    __shared__ __align__(16) _Float16 sB[128 * 64];
    int t = threadIdx.x;
    int row0 = rb * 128, col0 = cb * 128;
    int lane = t & 63, wave = t >> 6;
    int wm = wave >> 1, wn = wave & 1;
    int l31 = lane & 31;
    int lhi = lane >> 5;

    int koff = (mode == 1) ? ((cb >> 1) * 64) : 0;
    const _Float16* gA = A + (size_t)row0 * ldA + koff;
    const _Float16* gB = BT + (size_t)col0 * Kdim;

    int sR[4], sgl[4];
#pragma unroll
    for (int i = 0; i < 4; i++) {
        int m = i * 256 + t;
        sR[i] = m >> 3;
        sgl[i] = (m & 7) ^ (sR[i] & 7);
    }

    f32x16 acc[2][2] = {};

    for (int k0 = 0; k0 < Kdim; k0 += 64) {
        __syncthreads();
#pragma unroll
        for (int i = 0; i < 4; i++) {
            const _Float16* pa = gA + (size_t)sR[i] * ldA + k0 + sgl[i] * 8;
            const _Float16* pb = gB + (size_t)sR[i] * Kdim + k0 + sgl[i] * 8;
            async16(pa, sA + (i * 256 + t) * 8);
            async16(pb, sB + (i * 256 + t) * 8);
        }
        __syncthreads();
#pragma unroll
        for (int kk = 0; kk < 4; kk++) {
            int g = kk * 2 + lhi;
            half8 af[2], bf[2];
#pragma unroll
            for (int mt = 0; mt < 2; mt++) {
                int R = wm * 64 + mt * 32 + l31;
                int gp = g ^ (R & 7);
                af[mt] = *(const half8*)(sA + R * 64 + gp * 8);
            }
#pragma unroll
            for (int nt = 0; nt < 2; nt++) {
                int R = wn * 64 + nt * 32 + l31;
                int gp = g ^ (R & 7);
                bf[nt] = *(const half8*)(sB + R * 64 + gp * 8);
            }
#pragma unroll
            for (int mt = 0; mt < 2; mt++)
#pragma unroll
                for (int nt = 0; nt < 2; nt++)
                    acc[mt][nt] = __builtin_amdgcn_mfma_f32_32x32x16_f16(af[mt], bf[nt], acc[mt][nt], 0, 0, 0);
        }
    }

    int cb32 = col0 + wn * 64 + l31;
    int rb32 = row0 + wm * 64 + 4 * lhi;
    if (mode == 1) {
        _Float16* C16 = (_Float16*)C8;
#pragma unroll
        for (int mt = 0; mt < 2; mt++)
#pragma unroll
            for (int nt = 0; nt < 2; nt++) {
                int gc = cb32 + nt * 32;
                if (gc < Nfeat) {
#pragma unroll
                    for (int r = 0; r < 16; r++) {
                        int gr = rb32 + mt * 32 + (r & 3) + 8 * (r >> 2);
                        if (gr < M) C16[(size_t)gr * ld + gc] = (_Float16)elu1(elu1(acc[mt][nt][r]));
                    }
                }
            }
        return;
    }
#pragma unroll
    for (int mt = 0; mt < 2; mt++)
#pragma unroll
        for (int nt = 0; nt < 2; nt++) {
            int gc = cb32 + nt * 32;
            if (gc < Nfeat) {
#pragma unroll
                for (int r = 0; r < 16; r++) {
                    int gr = rb32 + mt * 32 + (r & 3) + 8 * (r >> 2);
                    if (gr < M) C8[(size_t)gr * ld + gc] = f2fp8(acc[mt][nt][r]);
                }
            } else if (gc < Nfeat + 12) {
                int j = gc - Nfeat;
#pragma unroll
                for (int r = 0; r < 16; r++) {
                    int gr = rb32 + mt * 32 + (r & 3) + 8 * (r >> 2);
                    if (gr < M) SPRE[(size_t)j * N_NODES + gr] = acc[mt][nt][r];
                }
            }
        }
}

// ---------------- layer 1: attention + x-aggregation (gather x, L2-resident) ----------
__global__ __launch_bounds__(256) void aggx1_kernel(const int* __restrict__ rowptr,
                                                    const int* __restrict__ esrc,
                                                    const float* __restrict__ SPRE,
                                                    const _Float16* __restrict__ A1,
                                                    _Float16* __restrict__ XB, int N) {
    int n = blockIdx.x;
    int h = threadIdx.x >> 6;
    int lane = threadIdx.x & 63;
    int start = rowptr[n], end = rowptr[n + 1];
    int cnt = end - start;
    const float* ss = SPRE + (size_t)h * N;
    float sd = SPRE[(size_t)(4 + h) * N + n];
    const unsigned char* Wb = (const unsigned char*)A1 + 2 * lane;
    float acc = 0.f;

    if (cnt <= 64) {
        int e = start + lane;
        bool act = e < end;
        int idx = act ? esrc[e] : 0;
        int voff = idx << 7;

        unsigned short wA[8], wB[8], wC[8], wD[8];
        auto ISSUE = [&](unsigned short (&buf)[8], int base) {
#pragma unroll
            for (int u = 0; u < 8; u++) {
                int off = __builtin_amdgcn_readlane(voff, base + u);
                buf[u] = *(const unsigned short*)(Wb + (unsigned)off);
            }
        };
        ISSUE(wA, 0);
        if (cnt > 8)  ISSUE(wB, 8);
        if (cnt > 16) ISSUE(wC, 16);
        if (cnt > 24) ISSUE(wD, 24);

        float sc = -1e30f;
        if (act) {
            sc = ss[idx] + sd;
            sc = sc > 0.f ? sc : ALPHA * sc;
        }
        float m = sc;
#pragma unroll
        for (int off = 1; off < 64; off <<= 1) m = fmaxf(m, __shfl_xor(m, off));
        float ptil = act ? __expf(sc - m) : 0.f;
        float s = ptil;
#pragma unroll
        for (int off = 1; off < 64; off <<= 1) s += __shfl_xor(s, off);
        float p = ptil * (1.f / (s + GAT_EPS));

        auto CONSUME = [&](unsigned short (&buf)[8], int base) {
#pragma unroll
            for (int u = 0; u < 8; u++) {
                float pj = rdlanef(p, base + u);
                acc += pj * (float)(*(const _Float16*)&buf[u]);
            }
        };
        CONSUME(wA, 0);
        if (cnt > 8)  { if (cnt > 32) ISSUE(wA, 32); CONSUME(wB, 8); }
        if (cnt > 16) { if (cnt > 40) ISSUE(wB, 40); CONSUME(wC, 16); }
        if (cnt > 24) { if (cnt > 48) ISSUE(wC, 48); CONSUME(wD, 24); }
        if (cnt > 32) { if (cnt > 56) ISSUE(wD, 56); CONSUME(wA, 32); }
        if (cnt > 40) CONSUME(wB, 40);
        if (cnt > 48) CONSUME(wC, 48);
        if (cnt > 56) CONSUME(wD, 56);
    } else {
        float m = -1e30f, s = 0.f;
        int sidx = 0; float ssc = -1e30f;
        for (int e0 = start; e0 < end; e0 += 64) {
            int e = e0 + lane;
            bool act = e < end;
            int idx = act ? esrc[e] : 0;
            float sc = -1e30f;
            if (act) {
                sc = ss[idx] + sd;
                sc = sc > 0.f ? sc : ALPHA * sc;
            }
            sidx = idx; ssc = sc;
            float mn = fmaxf(m, sc);
            s = s * __expf(m - mn) + (act ? __expf(sc - mn) : 0.f);
            m = mn;
        }
        float lm = m;
#pragma unroll
        for (int off = 1; off < 64; off <<= 1) m = fmaxf(m, __shfl_xor(m, off));
        float ptil = s * __expf(lm - m);
        s = ptil;
#pragma unroll
        for (int off = 1; off < 64; off <<= 1) s += __shfl_xor(s, off);
        float inv = 1.f / (s + GAT_EPS);

        int lastStart = start + (((end - start - 1) >> 6) << 6);
        for (int e0 = start; e0 < end; e0 += 64) {
            int e = e0 + lane;
            bool act = e < end;
            int idx; float p;
            if (e0 == lastStart) {
                idx = sidx;
                p = act ? __expf(ssc - m) * inv : 0.f;
            } else {
                idx = act ? esrc[e] : 0;
                float sc = -1e30f;
                if (act) {
                    sc = ss[idx] + sd;
                    sc = sc > 0.f ? sc : ALPHA * sc;
                }
                p = act ? __expf(sc - m) * inv : 0.f;
            }
            int cn = end - e0; if (cn > 64) cn = 64;
            for (int j = 0; j < cn; j++) {
                int ij = __builtin_amdgcn_readlane(idx, j);
                float pj = rdlanef(p, j);
                unsigned short w = *(const unsigned short*)(Wb + ((size_t)(unsigned)ij << 7));
                acc += pj * (float)(*(const _Float16*)&w);
            }
        }
    }

    XB[(size_t)n * 256 + h * 64 + lane] = (_Float16)acc;
}

// ---------------- layer 2 att+agg: row-gather (wave owns edge, 64 lanes x 16B = row) ----
__global__ __launch_bounds__(256) void attagg256_kernel(const int* __restrict__ rowptr,
                                                        const int* __restrict__ esrc,
                                                        const float* __restrict__ SPRE,
                                                        const unsigned char* __restrict__ WH8,
                                                        _Float16* __restrict__ X16,
                                                        int use_skip, int N) {
    __shared__ float Pp[4][66];
    __shared__ float part[4][1152];      // 64*18 per wave
    int n = blockIdx.x;
    int t = threadIdx.x;
    int wv = t >> 6;
    int lane = t & 63;
    int start = rowptr[n], end = rowptr[n + 1];
    int cnt = end - start;
    const float* ss = SPRE + (size_t)wv * N;
    float sd = SPRE[(size_t)(4 + wv) * N + n];

    if (cnt <= 64) {
        int e = start + lane;
        bool act = e < end;
        int idx = act ? esrc[e] : 0;

        const unsigned char* Wp = WH8 + lane * 16;
        uint4 w = {}, wnext = {};
        bool has0 = wv < cnt, has1 = wv + 4 < cnt;
        if (has0) {
            int i0 = __builtin_amdgcn_readlane(idx, wv);
            w = *(const uint4*)(Wp + ((size_t)(unsigned)i0 << 10));
        }
        if (has1) {
            int i1 = __builtin_amdgcn_readlane(idx, wv + 4);
            wnext = *(const uint4*)(Wp + ((size_t)(unsigned)i1 << 10));
        }

        float sc = -1e30f;
        if (act) {
            sc = ss[idx] + sd;
            sc = sc > 0.f ? sc : ALPHA * sc;
        }
        float m = sc;
#pragma unroll
        for (int off = 1; off < 64; off <<= 1) m = fmaxf(m, __shfl_xor(m, off));
        float ptil = act ? __expf(sc - m) : 0.f;
        float s = ptil;
#pragma unroll
        for (int off = 1; off < 64; off <<= 1) s += __shfl_xor(s, off);
        float p = ptil * (1.f / (s + GAT_EPS));
        Pp[wv][lane] = p;
        __syncthreads();

        f32x2 acc[8] = {};
        int hf = lane >> 4;
        if (has0) {
            int j = wv;
            for (;;) {
                uint4 w3 = w;
                bool have3 = j + 8 < cnt;
                if (have3) {
                    int i3 = __builtin_amdgcn_readlane(idx, j + 8);
                    w3 = *(const uint4*)(Wp + ((size_t)(unsigned)i3 << 10));
                }
                float pj = Pp[hf][j];
                f32x2 pv; pv.x = pj; pv.y = pj;
                acc[0] = pkfma(cvt8<false>(w.x), pv, acc[0]);
                acc[1] = pkfma(cvt8<true>(w.x),  pv, acc[1]);
                acc[2] = pkfma(cvt8<false>(w.y), pv, acc[2]);
                acc[3] = pkfma(cvt8<true>(w.y),  pv, acc[3]);
                acc[4] = pkfma(cvt8<false>(w.z), pv, acc[4]);
                acc[5] = pkfma(cvt8<true>(w.z),  pv, acc[5]);
                acc[6] = pkfma(cvt8<false>(w.w), pv, acc[6]);
                acc[7] = pkfma(cvt8<true>(w.w),  pv, acc[7]);
                j += 4;
                if (j >= cnt) break;
                w = wnext; wnext = w3;
            }
        }
#pragma unroll
        for (int k2 = 0; k2 < 8; k2++)
            *(f32x2*)&part[wv][lane * 18 + 2 * k2] = acc[k2];
    } else {
        for (int i = lane; i < 1152; i += 64) part[wv][i] = 0.f;
        const unsigned char* Wb = WH8 + wv * 256 + lane * 4;
        float a0 = 0.f, a1 = 0.f, a2 = 0.f, a3 = 0.f;
        float m = -1e30f, s = 0.f;
        int sidx = 0; float ssc = -1e30f;
        for (int e0 = start; e0 < end; e0 += 64) {
            int e = e0 + lane;
            bool act = e < end;
            int idx = act ? esrc[e] : 0;
            float sc = -1e30f;
            if (act) {
                sc = ss[idx] + sd;
                sc = sc > 0.f ? sc : ALPHA * sc;
            }
            sidx = idx; ssc = sc;
            float mn = fmaxf(m, sc);
            s = s * __expf(m - mn) + (act ? __expf(sc - mn) : 0.f);
            m = mn;
        }
        float lm = m;
#pragma unroll
        for (int off = 1; off < 64; off <<= 1) m = fmaxf(m, __shfl_xor(m, off));
        float ptil = s * __expf(lm - m);
        s = ptil;
#pragma unroll
        for (int off = 1; off < 64; off <<= 1) s += __shfl_xor(s, off);
        float inv = 1.f / (s + GAT_EPS);

        int lastStart = start + (((end - start - 1) >> 6) << 6);
        for (int e0 = start; e0 < end; e0 += 64) {
            int e = e0 + lane;
            bool act = e < end;
            int idx; float p;
            if (e0 == lastStart) {
                idx = sidx;
                p = act ? __expf(ssc - m) * inv : 0.f;
            } else {
                idx = act ? esrc[e] : 0;
                float sc = -1e30f;
                if (act) {
                    sc = ss[idx] + sd;
                    sc = sc > 0.f ? sc : ALPHA * sc;
                }
                p = act ? __expf(sc - m) * inv : 0.f;
            }
            int cn = end - e0; if (cn > 64) cn = 64;
            for (int j = 0; j < cn; j++) {
                int ij = __builtin_amdgcn_readlane(idx, j);
                float pj = rdlanef(p, j);
                unsigned int ww = *(const unsigned int*)(Wb + (size_t)ij * 1024);
                f32x2 lo = __builtin_amdgcn_cvt_pk_f32_fp8((int)ww, false);
                f32x2 hi = __builtin_amdgcn_cvt_pk_f32_fp8((int)ww, true);
                a0 += pj * lo.x; a1 += pj * lo.y; a2 += pj * hi.x; a3 += pj * hi.y;
            }
        }
        int cb = wv * 256 + lane * 4;
        int off0 = (cb >> 4) * 18 + (cb & 15);
        part[wv][off0]     = a0;
        part[wv][off0 + 1] = a1;
        part[wv][off0 + 2] = a2;
        part[wv][off0 + 3] = a3;
    }
    __syncthreads();

    int off = (t >> 2) * 18 + 4 * (t & 3);
    float a0 = part[0][off]     + part[1][off]     + part[2][off]     + part[3][off];
    float a1 = part[0][off + 1] + part[1][off + 1] + part[2][off + 1] + part[3][off + 1];
    float a2 = part[0][off + 2] + part[1][off + 2] + part[2][off + 2] + part[3][off + 2];
    float a3 = part[0][off + 3] + part[1][off + 3] + part[2][off + 3] + part[3][off + 3];

    size_t o = (size_t)n * 1024 + t * 4;
    float v0, v1, v2, v3;
    if (use_skip) {
        half4t sk = *(const half4t*)(X16 + o);
        v0 = elu1(elu1(a0) + (float)sk.x);
        v1 = elu1(elu1(a1) + (float)sk.y);
        v2 = elu1(elu1(a2) + (float)sk.z);
        v3 = elu1(elu1(a3) + (float)sk.w);
    } else {
        v0 = elu1(elu1(a0)); v1 = elu1(elu1(a1));
        v2 = elu1(elu1(a2)); v3 = elu1(elu1(a3));
    }
    half4t r;
    r.x = (_Float16)v0; r.y = (_Float16)v1; r.z = (_Float16)v2; r.w = (_Float16)v3;
    *(half4t*)(X16 + o) = r;
}

// ---------------- layer 3 att+agg: row-gather, heads at 128B stride, ld=1024 ----------
// 48 lanes x 16B = 768B = 6 heads x 128B exactly -> hf = lane>>3, no head straddle
// (r8 bug: 124B stride straddled 16B lane slots). Cols 121..127 are exact pack zeros.
__global__ __launch_bounds__(384) void attagg726_kernel(const int* __restrict__ rowptr,
                                                        const int* __restrict__ esrc,
                                                        const float* __restrict__ SPRE,
                                                        const unsigned char* __restrict__ WH8,
                                                        float* __restrict__ out, int N) {
    __shared__ float Pp[6][66];
    __shared__ float part[6][864];       // 48*18 per wave
    __shared__ float red[768];
    int n = blockIdx.x;
    int t = threadIdx.x;
    int wv = t >> 6;
    int lane = t & 63;
    int start = rowptr[n], end = rowptr[n + 1];
    int cnt = end - start;
    const float* ss = SPRE + (size_t)wv * N;
    float sd = SPRE[(size_t)(6 + wv) * N + n];

    if (cnt <= 64) {
        int e = start + lane;
        bool act = e < end;
        int idx = act ? esrc[e] : 0;

        const unsigned char* Wp = WH8 + lane * 16;
        uint4 w = {}, wnext = {};
        bool has0 = wv < cnt, has1 = wv + 6 < cnt;
        if (lane < 48) {
            if (has0) {
                int i0 = __builtin_amdgcn_readlane(idx, wv);
                w = *(const uint4*)(Wp + ((size_t)(unsigned)i0 << 10));
            }
            if (has1) {
                int i1 = __builtin_amdgcn_readlane(idx, wv + 6);
                wnext = *(const uint4*)(Wp + ((size_t)(unsigned)i1 << 10));
            }
        }

        float sc = -1e30f;
        if (act) {
            sc = ss[idx] + sd;
            sc = sc > 0.f ? sc : ALPHA * sc;
        }
        float m = sc;
#pragma unroll
        for (int off = 1; off < 64; off <<= 1) m = fmaxf(m, __shfl_xor(m, off));
        float ptil = act ? __expf(sc - m) : 0.f;
        float s = ptil;
#pragma unroll
        for (int off = 1; off < 64; off <<= 1) s += __shfl_xor(s, off);
        float p = ptil * (1.f / (s + GAT_EPS));
        Pp[wv][lane] = p;
        __syncthreads();

        f32x2 acc[8] = {};
        if (lane < 48 && has0) {
            int hf = lane >> 3;
            int j = wv;
            for (;;) {
                uint4 w3 = w;
                bool have3 = j + 12 < cnt;
                if (have3) {
                    int i3 = __builtin_amdgcn_readlane(idx, j + 12);
                    w3 = *(const uint4*)(Wp + ((size_t)(unsigned)i3 << 10));
                }
                float pj = Pp[hf][j];
                f32x2 pv; pv.x = pj; pv.y = pj;
                acc[0] = pkfma(cvt8<false>(w.x), pv, acc[0]);
                acc[1] = pkfma(cvt8<true>(w.x),  pv, acc[1]);
                acc[2] = pkfma(cvt8<false>(w.y), pv, acc[2]);
                acc[3] = pkfma(cvt8<true>(w.y),  pv, acc[3]);
                acc[4] = pkfma(cvt8<false>(w.z), pv, acc[4]);
                acc[5] = pkfma(cvt8<true>(w.z),  pv, acc[5]);
                acc[6] = pkfma(cvt8<false>(w.w), pv, acc[6]);
                acc[7] = pkfma(cvt8<true>(w.w),  pv, acc[7]);
                j += 6;
                if (j >= cnt) break;
                w = wnext; wnext = w3;
            }
        }
        if (lane < 48) {
#pragma unroll
            for (int k2 = 0; k2 < 8; k2++)
                *(f32x2*)&part[wv][lane * 18 + 2 * k2] = acc[k2];
        }
    } else {
        // fallback: per-head chunked (h = wv); all 64 lanes (cols 2*lane <= 127,
        // cols 121..127 are zeros -> harmless)
        for (int i = lane; i < 864; i += 64) part[wv][i] = 0.f;
        const unsigned char* Wb = WH8 + wv * 128 + 2 * lane;
        float a0 = 0.f, a1 = 0.f;
        float m = -1e30f, s = 0.f;
        int sidx = 0; float ssc = -1e30f;
        for (int e0 = start; e0 < end; e0 += 64) {
            int e = e0 + lane;
            bool act = e < end;
            int idx = act ? esrc[e] : 0;
            float sc = -1e30f;
            if (act) {
                sc = ss[idx] + sd;
                sc = sc > 0.f ? sc : ALPHA * sc;
            }
            sidx = idx; ssc = sc;
            float mn = fmaxf(m, sc);
            s = s * __expf(m - mn) + (act ? __expf(sc - mn) : 0.f);
            m = mn;
        }
        float lm = m;
#pragma unroll
        for (int off = 1; off < 64; off <<= 1) m = fmaxf(m, __shfl_xor(m, off));
        float ptil = s * __expf(lm - m);
        s = ptil;
#pragma unroll
        for (int off = 1; off < 64; off <<= 1) s += __shfl_xor(s, off);
        float inv = 1.f / (s + GAT_EPS);

        int lastStart = start + (((end - start - 1) >> 6) << 6);
        for (int e0 = start; e0 < end; e0 += 64) {
            int e = e0 + lane;
            bool act = e < end;
            int idx; float p;
            if (e0 == lastStart) {
                idx = sidx;
                p = act ? __expf(ssc - m) * inv : 0.f;
            } else {
                idx = act ? esrc[e] : 0;
                float sc = -1e30f;
                if (act) {
                    sc = ss[idx] + sd;
                    sc = sc > 0.f ? sc : ALPHA * sc;
                }
                p = act ? __expf(sc - m) * inv : 0.f;
            }
            int cn = end - e0; if (cn > 64) cn = 64;
            for (int j = 0; j < cn; j++) {
                int ij = __builtin_amdgcn_readlane(idx, j);
                float pj = rdlanef(p, j);
                unsigned short ww = *(const unsigned short*)(Wb + ((size_t)(unsigned)ij << 10));
                f32x2 f = __builtin_amdgcn_cvt_pk_f32_fp8((int)ww, false);
                a0 += pj * f.x; a1 += pj * f.y;
            }
        }
        int c0 = wv * 128 + 2 * lane;
        part[wv][(c0 >> 4) * 18 + (c0 & 15)] = a0;
        int c1 = c0 + 1;
        part[wv][(c1 >> 4) * 18 + (c1 & 15)] = a1;
    }
    __syncthreads();

    for (int c = t; c < 768; c += 384) {
        int off = (c >> 4) * 18 + (c & 15);
        red[c] = part[0][off] + part[1][off] + part[2][off] +
                 part[3][off] + part[4][off] + part[5][off];
    }
    __syncthreads();
    if (t < 121) {
        float tot = (red[t] + red[128 + t] + red[256 + t] +
                     red[384 + t] + red[512 + t] + red[640 + t]) * (1.f / 6.f);
        out[(size_t)n * 121 + t] = 1.f / (1.f + __expf(-tot));
    }
}

extern "C" void kernel_launch(void* const* d_in, const int* in_sizes, int n_in,
                              void* d_out, int out_size, void* d_ws, size_t ws_size,
                              hipStream_t stream) {
    const float* x  = (const float*)d_in[0];
    const int*   ei = (const int*)d_in[1];
    const float* W1 = (const float*)d_in[2];
    const float* a1 = (const float*)d_in[3];
    const float* W2 = (const float*)d_in[4];
    const float* a2 = (const float*)d_in[5];
    const float* W3 = (const float*)d_in[6];
    const float* a3 = (const float*)d_in[7];
    float* out = (float*)d_out;
    const int N = N_NODES, E = N_EDGES;
    const int* src = ei;
    const int* dst = ei + E;

    char* ws = (char*)d_ws;
    size_t off = 0;
    auto alloc = [&](size_t b) { size_t o = off; off += (b + 255) & ~(size_t)255; return o; };
    _Float16* X16  = (_Float16*)(ws + alloc((size_t)MPAD * 1024 * 2));  // x1 then x2 (fp16)
    unsigned char* WH8 = (unsigned char*)(ws + alloc((size_t)MPAD * 1024)); // per-layer Wh (fp8)
    _Float16* BT16 = (_Float16*)(ws + alloc((size_t)BT_ROWS * 1024 * 2));
    _Float16* A1   = (_Float16*)(ws + alloc((size_t)MPAD * 64 * 2));
    _Float16* BT1  = (_Float16*)(ws + alloc((size_t)BT_ROWS * 64 * 2));
    _Float16* XB   = (_Float16*)(ws + alloc((size_t)MPAD * 256 * 2));  // layer-1 xbar
    _Float16* BTS  = (_Float16*)(ws + alloc((size_t)128 * 64 * 2));    // layer-1 score cols
    float* SPRE   = (float*)(ws + alloc((size_t)12 * N * 4));
    int*   rowptr = (int*)(ws + alloc((size_t)(N + 1) * 4));
    int*   cursor = (int*)(ws + alloc((size_t)N * 4));
    int*   counts = (int*)(ws + alloc((size_t)N * 4));
    int*   excl   = (int*)(ws + alloc((size_t)N * 4));
    int*   partial= (int*)(ws + alloc((size_t)SCAN_BLKS * 4));
    int*   esrc   = (int*)(ws + alloc((size_t)E * 4));

    // CSR by dst
    hipMemsetAsync(counts, 0, (size_t)N * 4, stream);
    hist_kernel<<<(E + 255) / 256, 256, 0, stream>>>(dst, counts, E);
    scan1_kernel<<<SCAN_BLKS, 256, 0, stream>>>(counts, excl, partial, N);
    scan2_kernel<<<1, 128, 0, stream>>>(partial);
    scan3_kernel<<<SCAN_BLKS, 256, 0, stream>>>(excl, partial, rowptr, cursor, N, E);
    scatter_kernel<<<(E + 255) / 256, 256, 0, stream>>>(src, dst, cursor, esrc, E);
    hipMemsetAsync(X16 + (size_t)N * 1024, 0, (size_t)(MPAD - N) * 1024 * 2, stream);
    hipMemsetAsync(XB + (size_t)N * 256, 0, (size_t)(MPAD - N) * 256 * 2, stream);

    // ---- layer 1: scores from x@Wtil; aggregate x (L2-resident); block-diag GEMM ----
    pack_x16<<<MPAD * 64 / 256, 256, 0, stream>>>(x, A1);
    pack_bt1<<<1024 * 64 / 256, 256, 0, stream>>>(W1, BT1);
    wtilde_kernel<<<dim3(64, 8), 64, 0, stream>>>(W1, a1, BTS, 50, 64, 256, 4, 0);
    gemm_f16<<<8 * RHI * 1, 256, 0, stream>>>(A1, BTS, WH8, SPRE, N, 0, 1024, 64, 1, 64, 0);
    aggx1_kernel<<<N, 256, 0, stream>>>(rowptr, esrc, SPRE, A1, XB, N);
    gemm_f16<<<8 * RHI * 8, 256, 0, stream>>>(XB, BT1, (unsigned char*)X16, SPRE, N, 1024, 1024, 64, 8, 256, 1);

    // ---- layer 2: 1024 -> 4x256 concat + skip ----
    pack_bt16<<<dim3(4, 1024), 256, 0, stream>>>(W2, BT16, 256, 256, 1024);
    wtilde_kernel<<<dim3(1024, 8), 64, 0, stream>>>(W2, a2, BT16, 1024, 1024, 256, 4, 1024);
    gemm_f16<<<8 * RHI * 9, 256, 0, stream>>>(X16, BT16, WH8, SPRE, N, 1024, 1024, 1024, 9, 1024, 0);
    attagg256_kernel<<<N, 256, 0, stream>>>(rowptr, esrc, SPRE, WH8, X16, 1, N);

    // ---- layer 3: 1024 -> 6 heads @ 128-col stride (121 real + zero pad), ld=1024 ----
    pack_bt16<<<dim3(4, 768), 256, 0, stream>>>(W3, BT16, 121, 128, 768);
    wtilde_kernel<<<dim3(1024, 12), 64, 0, stream>>>(W3, a3, BT16, 1024, 1024, 121, 6, 768);
    gemm_f16<<<8 * RHI * 7, 256, 0, stream>>>(X16, BT16, WH8, SPRE, N, 768, 1024, 1024, 7, 1024, 0);
    attagg726_kernel<<<N, 384, 0, stream>>>(rowptr, esrc, SPRE, WH8, out, N);
}